// Round 3
// baseline (772.574 us; speedup 1.0000x reference)
//
#include <hip/hip_runtime.h>
#include <hip/hip_bf16.h>
#include <math.h>

typedef __bf16 bf16x8 __attribute__((ext_vector_type(8)));
typedef short  s16x8  __attribute__((ext_vector_type(8)));
typedef float  f32x4  __attribute__((ext_vector_type(4)));
typedef unsigned short u16;

// ---- sizes ----
#define NN 32
#define CC 256
#define HH 56
#define WW 56
#define HP 68            // padded spatial (6 halo each side)
#define XP2_BYTES 75759616ull            // 32*68*68*256*2
#define XP2_OFF 0ull
#define WT4_OFF 75759616ull              // 200*2*8*1024 = 3276800 bytes
#define T1_OFF  79036416ull              // 32*256*56*4 = 1835008
#define T9_OFF  80871424ull              // 32*56*56*4

__device__ inline u16 f2bf(float f) {
    unsigned int u = __builtin_bit_cast(unsigned int, f);
    u = (u + 0x7fffu + ((u >> 16) & 1u)) >> 16;   // RNE
    return (u16)u;
}

__device__ inline void gl_lds16(const char* g, char* l) {
    __builtin_amdgcn_global_load_lds(
        (const __attribute__((address_space(1))) unsigned int*)g,
        (__attribute__((address_space(3))) unsigned int*)l, 16, 0, 0);
}

// ---- zero xp2 (halo must be 0; ws is poisoned 0xAA each call) ----
__global__ void zero_xp2(u16* __restrict__ xp2, size_t n16) {
    size_t i = (size_t)blockIdx.x * blockDim.x + threadIdx.x;
    size_t stride = (size_t)gridDim.x * blockDim.x;
    uint4* p = (uint4*)xp2;
    uint4 z; z.x = z.y = z.z = z.w = 0u;
    for (; i < n16; i += stride) p[i] = z;
}

// ---- pack w7 -> wt4[k][g][chunk][slot(64)][16B], slot = q*16+m ----
// slot q*16+m holds cout g*128+chunk*16+m, cins [k-slice, q*8 .. q*8+8)
__global__ __launch_bounds__(256)
void pack_w(const float* __restrict__ w7, u16* __restrict__ wt4) {
    int idx = blockIdx.x * 256 + threadIdx.x;    // 256*6400 total
    int c_out = idx / 6400;
    int k0 = idx - c_out * 6400;
    int cin = k0 / 25;
    int tap = k0 - cin * 25;
    int k = tap * 8 + (cin >> 5);
    int ci = cin & 31;
    int q = ci >> 3, j = ci & 7;
    int g = c_out >> 7, ch = (c_out >> 4) & 7, m = c_out & 15;
    wt4[(((size_t)(k * 2 + g) * 8 + ch) * 64 + q * 16 + m) * 8 + j] = f2bf(w7[idx]);
}

// ---- fused: pack x->xp2 (bf16, c innermost) + t1 (row max) + t9 (softmax) ----
__global__ __launch_bounds__(256)
void prep(const float* __restrict__ x, const float* __restrict__ w6,
          float* __restrict__ t1, float* __restrict__ t9, u16* __restrict__ xp2) {
    const int n = blockIdx.x / HH;
    const int h = blockIdx.x % HH;
    const int tid = threadIdx.x;
    const int wave = tid >> 6;
    const int lane = tid & 63;
    const bool valid = lane < WW;
    const int wl = valid ? lane : (WW - 1);
    const float* xrow = x + ((size_t)(n * CC) * HH + h) * WW;
    __shared__ float sbuf[4 * 64];
    __shared__ u16 tile[56 * 264];   // row stride 264 u16 = 528B (16B pad)
    float accw = 0.f;
    s16x8 pk;
    for (int i = 0; i < 64; ++i) {
        int c = wave * 64 + i;
        float xv = xrow[(size_t)c * (HH * WW) + wl];
        float xm = valid ? xv : -INFINITY;
#pragma unroll
        for (int off = 32; off > 0; off >>= 1)
            xm = fmaxf(xm, __shfl_xor(xm, off));
        if (lane == 0) t1[(size_t)(n * CC + c) * HH + h] = xm;
        if (valid) accw += tanhf(fmaxf(xv, 0.f)) * w6[c];
        pk[i & 7] = (short)f2bf(xv);
        if ((i & 7) == 7 && valid)
            *(s16x8*)(tile + lane * 264 + (wave * 8 + (i >> 3)) * 8) = pk;
    }
    sbuf[wave * 64 + lane] = accw;
    __syncthreads();
    if (wave == 0) {
        float s = sbuf[lane] + sbuf[64 + lane] + sbuf[128 + lane] + sbuf[192 + lane];
        float sm = valid ? s : -INFINITY;
        float mx = sm;
#pragma unroll
        for (int off = 32; off > 0; off >>= 1)
            mx = fmaxf(mx, __shfl_xor(mx, off));
        float e = valid ? expf(s - mx) : 0.f;
        float tot = e;
#pragma unroll
        for (int off = 32; off > 0; off >>= 1)
            tot += __shfl_xor(tot, off);
        if (valid) t9[((size_t)n * HH + h) * WW + lane] = e / tot;
    }
    // coalesced write of the packed (w,c) tile: 56*32 granules of 16B
    u16* dst = xp2 + (((size_t)n * HP + (h + 6)) * HP + 6) * CC;
    for (int g = tid; g < 56 * 32; g += 256) {
        int w = g >> 5, cg = g & 31;
        *(s16x8*)(dst + (size_t)w * CC + cg * 8) = *(const s16x8*)(tile + w * 264 + cg * 8);
    }
}

// ---- main: implicit GEMM, M=128 cout x N=128 flat-spatial, BK=32 ----
// 256 thr = 4 waves (2 cout-groups x 2 pos-groups), wave tile 64x64,
// double-buffered LDS via global_load_lds; slots permuted so ALL frag reads
// are base + lane*16 (sequential -> conflict-free).
__global__ __launch_bounds__(256, 3)
void conv_main(const char* __restrict__ xp2b, const char* __restrict__ wt4b,
               const float* __restrict__ x, const float* __restrict__ t1,
               const float* __restrict__ t9, float* __restrict__ out) {
    // XCD-contiguous swizzle: assume xcd = blockIdx % 8; give each XCD 98
    // consecutive tiles, both g of a tile adjacent (share B data in L2).
    const int u = blockIdx.x;
    const int xcd = u & 7;
    const int i0 = u >> 3;                 // 0..195
    const int tile = xcd * 98 + (i0 >> 1);
    const int g = i0 & 1;
    const int tid = threadIdx.x;
    const int wid = tid >> 6;
    const int lane = tid & 63;
    const int m = lane & 15;
    const int q = lane >> 4;
    const int wgc = wid & 1;          // cout sub-group (64)
    const int wgp = wid >> 1;         // pos sub-group (64)

    __shared__ __align__(16) char smem[2][16384];  // per buf: A 8KB + B 8KB

    // B staging bases: wave 2,3 chunk cb=(wid-2)*4+i covers positions
    // tile*128+cb*16+(lane&15); lane>>4 selects 16B granule of the 64B slice.
    unsigned vb[4] = {0, 0, 0, 0};
    if (wid >= 2) {
#pragma unroll
        for (int i = 0; i < 4; ++i) {
            int p = tile * 128 + ((wid - 2) * 4 + i) * 16 + (lane & 15);
            int n = p / (HH * WW);
            int rem = p - n * (HH * WW);
            int hh = rem / WW;
            int ww = rem - hh * WW;
            vb[i] = ((((unsigned)n * HP + hh + 6) * HP) + ww + 6) * 512 + (lane >> 4) * 16;
        }
    }

    auto stage = [&](int kn, int nb) {
        char* dst = smem[nb];
        if (wid < 2) {
            const char* gsrc = wt4b + (size_t)(kn * 2 + g) * 8192 + wid * 4096 + lane * 16;
            char* d = dst + wid * 4096 + lane * 16;
#pragma unroll
            for (int i = 0; i < 4; ++i) gl_lds16(gsrc + i * 1024, d + i * 1024);
        } else {
            const int tp = kn >> 3, ch = kn & 7;
            const ptrdiff_t tapoff =
                (ptrdiff_t)((tp / 5) * 3 - 6) * (HP * 512) +
                (ptrdiff_t)((tp % 5) * 3 - 6) * 512 + ch * 64;
            const char* gb = xp2b + tapoff;
            char* d = dst + 8192 + (wid - 2) * 4096 + lane * 16;
#pragma unroll
            for (int i = 0; i < 4; ++i) gl_lds16(gb + vb[i], d + i * 1024);
        }
    };

    f32x4 acc[4][4];
#pragma unroll
    for (int ct = 0; ct < 4; ++ct)
#pragma unroll
        for (int st = 0; st < 4; ++st) {
            acc[ct][st][0] = 0.f; acc[ct][st][1] = 0.f;
            acc[ct][st][2] = 0.f; acc[ct][st][3] = 0.f;
        }

    // frag reads: chunk*1024 + lane*16 (sequential per wave -> no conflicts)
    const int aOff = wgc * 4096 + lane * 16;          // + ct*1024
    const int bOff = 8192 + wgp * 4096 + lane * 16;   // + st*1024

    stage(0, 0);
    for (int k = 0; k < 200; ++k) {
        __syncthreads();           // buf[k&1] staged; prev compute done
        if (k < 199) stage(k + 1, (k + 1) & 1);
        const char* bp = smem[k & 1];
        bf16x8 av[4], bv[4];
#pragma unroll
        for (int ct = 0; ct < 4; ++ct)
            av[ct] = *(const bf16x8*)(const void*)(bp + aOff + ct * 1024);
#pragma unroll
        for (int st = 0; st < 4; ++st)
            bv[st] = *(const bf16x8*)(const void*)(bp + bOff + st * 1024);
#pragma unroll
        for (int ct = 0; ct < 4; ++ct)
#pragma unroll
            for (int st = 0; st < 4; ++st)
                acc[ct][st] = __builtin_amdgcn_mfma_f32_16x16x32_bf16(
                    av[ct], bv[st], acc[ct][st], 0, 0, 0);
    }

    // epilogue: out = t1 - (t9 * roll(x,2,h) + x * t7)
#pragma unroll
    for (int st = 0; st < 4; ++st) {
        const int p = tile * 128 + wgp * 64 + st * 16 + m;
        const int n = p / (HH * WW);
        const int rem = p - n * (HH * WW);
        const int h = rem / WW;
        const int w = rem - h * WW;
        const float t9v = t9[((size_t)n * HH + h) * WW + w];
        const int hprev = (h >= 2) ? (h - 2) : (h + HH - 2);
#pragma unroll
        for (int ct = 0; ct < 4; ++ct) {
            const int c = g * 128 + wgc * 64 + ct * 16 + q * 4;
#pragma unroll
            for (int r = 0; r < 4; ++r) {
                const size_t rowi = (size_t)(n * CC + c + r) * HH;
                const float t1v = t1[rowi + h];
                const float xv = x[(rowi + h) * WW + w];
                const float xr = x[(rowi + hprev) * WW + w];
                out[(rowi + h) * WW + w] = t1v - (t9v * xr + xv * acc[ct][st][r]);
            }
        }
    }
}

extern "C" void kernel_launch(void* const* d_in, const int* in_sizes, int n_in,
                              void* d_out, int out_size, void* d_ws, size_t ws_size,
                              hipStream_t stream) {
    const float* x  = (const float*)d_in[0];
    const float* w6 = (const float*)d_in[1];
    const float* w7 = (const float*)d_in[2];
    float* out = (float*)d_out;
    char* ws = (char*)d_ws;
    u16*   xp2 = (u16*)(ws + XP2_OFF);
    u16*   wt4 = (u16*)(ws + WT4_OFF);
    float* t1  = (float*)(ws + T1_OFF);
    float* t9  = (float*)(ws + T9_OFF);

    zero_xp2<<<dim3(2048), dim3(256), 0, stream>>>(xp2, XP2_BYTES / 16);
    pack_w<<<dim3(6400), dim3(256), 0, stream>>>(w7, wt4);
    prep<<<dim3(NN * HH), dim3(256), 0, stream>>>(x, w6, t1, t9, xp2);
    conv_main<<<dim3(1568), dim3(256), 0, stream>>>((const char*)xp2, (const char*)wt4,
                                                    x, t1, t9, out);
}